// Round 2
// baseline (119.229 us; speedup 1.0000x reference)
//
#include <hip/hip_runtime.h>

#define IN_FEATS 128
#define HIDDEN 32

// ---------------------------------------------------------------------------
// Kernel 1: per-node precompute  Ps = embed @ W1s.T, Pd = embed @ W1d.T
// One thread per node. W1 accesses are wave-uniform -> scalar loads.
// Embed staged transposed in LDS for conflict-free per-lane register fill.
// ---------------------------------------------------------------------------
__global__ __launch_bounds__(256) void precompute_ps_pd(
    const float* __restrict__ embed,
    const float* __restrict__ W1,
    float* __restrict__ Ps,
    float* __restrict__ Pd,
    int n_nodes)
{
    // 32 features x (256 nodes + 8 pad): stride 264 words, 264%32==8 ->
    // read addr (k*264+t) over 64 lanes hits each bank exactly twice (free).
    __shared__ float e_t[32][264];
    const int t = threadIdx.x;
    const int node0 = blockIdx.x * 256;
    const int node = node0 + t;

    float acc_s[HIDDEN], acc_d[HIDDEN];
#pragma unroll
    for (int j = 0; j < HIDDEN; ++j) { acc_s[j] = 0.f; acc_d[j] = 0.f; }

    for (int c = 0; c < 4; ++c) {   // 4 chunks of 32 features
        __syncthreads();
        // Stage embed[node0..node0+255][c*32 .. c*32+31] transposed into LDS.
        // 2048 float4 loads, 8 per thread, lane-contiguous in flat index.
#pragma unroll
        for (int i = 0; i < 8; ++i) {
            const int idx = i * 256 + t;
            const int nl = idx >> 3;   // local node 0..255
            const int q  = idx & 7;    // float4 index within 32-feat chunk
            const int g  = node0 + nl;
            if (g < n_nodes) {
                const float4 v = *reinterpret_cast<const float4*>(
                    embed + (size_t)g * IN_FEATS + c * 32 + q * 4);
                e_t[q * 4 + 0][nl] = v.x;
                e_t[q * 4 + 1][nl] = v.y;
                e_t[q * 4 + 2][nl] = v.z;
                e_t[q * 4 + 3][nl] = v.w;
            }
        }
        __syncthreads();
        if (node < n_nodes) {
            float e[32];
#pragma unroll
            for (int k = 0; k < 32; ++k) e[k] = e_t[k][t];
            // W1 index has no threadIdx dependence -> uniform -> s_load path.
#pragma unroll
            for (int h = 0; h < HIDDEN; ++h) {
                float as = acc_s[h], ad = acc_d[h];
#pragma unroll
                for (int k = 0; k < 32; ++k) {
                    as = fmaf(e[k], W1[h * 256 + c * 32 + k], as);
                    ad = fmaf(e[k], W1[h * 256 + 128 + c * 32 + k], ad);
                }
                acc_s[h] = as; acc_d[h] = ad;
            }
        }
    }

    if (node < n_nodes) {
#pragma unroll
        for (int q = 0; q < 8; ++q) {
            const float4 vs = make_float4(acc_s[q*4+0], acc_s[q*4+1], acc_s[q*4+2], acc_s[q*4+3]);
            const float4 vd = make_float4(acc_d[q*4+0], acc_d[q*4+1], acc_d[q*4+2], acc_d[q*4+3]);
            *reinterpret_cast<float4*>(Ps + (size_t)node * HIDDEN + q * 4) = vs;
            *reinterpret_cast<float4*>(Pd + (size_t)node * HIDDEN + q * 4) = vd;
        }
    }
}

// ---------------------------------------------------------------------------
// Kernel 2: per-edge  logits = relu(Ps[src] + Pd[dst] + b1) @ W2.T + b2
// One thread per edge; 16 float4 gathers (tables are L2/L3-resident).
// ---------------------------------------------------------------------------
__global__ __launch_bounds__(256) void edge_classify(
    const int* __restrict__ src,
    const int* __restrict__ dst,
    const float* __restrict__ Ps,
    const float* __restrict__ Pd,
    const float* __restrict__ b1,
    const float* __restrict__ W2,
    const float* __restrict__ b2,
    float* __restrict__ out,
    int n_edges)
{
    const int e = blockIdx.x * 256 + threadIdx.x;
    if (e >= n_edges) return;
    const int s = src[e];
    const int d = dst[e];
    const float4* ps = reinterpret_cast<const float4*>(Ps + (size_t)s * HIDDEN);
    const float4* pd = reinterpret_cast<const float4*>(Pd + (size_t)d * HIDDEN);

    float4 a[8], b[8];
#pragma unroll
    for (int q = 0; q < 8; ++q) { a[q] = ps[q]; b[q] = pd[q]; }

    float l0 = b2[0], l1 = b2[1];
#pragma unroll
    for (int q = 0; q < 8; ++q) {
        const float va[4] = {a[q].x, a[q].y, a[q].z, a[q].w};
        const float vb[4] = {b[q].x, b[q].y, b[q].z, b[q].w};
#pragma unroll
        for (int j = 0; j < 4; ++j) {
            const int k = q * 4 + j;
            float h = va[j] + vb[j] + b1[k];
            h = fmaxf(h, 0.f);
            l0 = fmaf(h, W2[k], l0);
            l1 = fmaf(h, W2[HIDDEN + k], l1);
        }
    }
    *reinterpret_cast<float2*>(out + (size_t)e * 2) = make_float2(l0, l1);
}

// ---------------------------------------------------------------------------
// Fallback (only if workspace too small): direct per-edge computation.
// ---------------------------------------------------------------------------
__global__ __launch_bounds__(256) void edge_direct(
    const int* __restrict__ src, const int* __restrict__ dst,
    const float* __restrict__ embed,
    const float* __restrict__ W1, const float* __restrict__ b1,
    const float* __restrict__ W2, const float* __restrict__ b2,
    float* __restrict__ out, int n_edges)
{
    const int e = blockIdx.x * 256 + threadIdx.x;
    if (e >= n_edges) return;
    const int s = src[e], d = dst[e];
    const float* se = embed + (size_t)s * IN_FEATS;
    const float* de = embed + (size_t)d * IN_FEATS;

    float acc[HIDDEN];
#pragma unroll
    for (int h = 0; h < HIDDEN; ++h) acc[h] = b1[h];

    for (int c = 0; c < 4; ++c) {
        float es[32], ed[32];
#pragma unroll
        for (int q = 0; q < 8; ++q) {
            const float4 v = *reinterpret_cast<const float4*>(se + c * 32 + q * 4);
            es[q*4+0] = v.x; es[q*4+1] = v.y; es[q*4+2] = v.z; es[q*4+3] = v.w;
            const float4 w = *reinterpret_cast<const float4*>(de + c * 32 + q * 4);
            ed[q*4+0] = w.x; ed[q*4+1] = w.y; ed[q*4+2] = w.z; ed[q*4+3] = w.w;
        }
#pragma unroll
        for (int h = 0; h < HIDDEN; ++h) {
            float acch = acc[h];
#pragma unroll
            for (int k = 0; k < 32; ++k) {
                acch = fmaf(es[k], W1[h * 256 + c * 32 + k], acch);
                acch = fmaf(ed[k], W1[h * 256 + 128 + c * 32 + k], acch);
            }
            acc[h] = acch;
        }
    }

    float l0 = b2[0], l1 = b2[1];
#pragma unroll
    for (int h = 0; h < HIDDEN; ++h) {
        const float hh = fmaxf(acc[h], 0.f);
        l0 = fmaf(hh, W2[h], l0);
        l1 = fmaf(hh, W2[HIDDEN + h], l1);
    }
    *reinterpret_cast<float2*>(out + (size_t)e * 2) = make_float2(l0, l1);
}

extern "C" void kernel_launch(void* const* d_in, const int* in_sizes, int n_in,
                              void* d_out, int out_size, void* d_ws, size_t ws_size,
                              hipStream_t stream)
{
    const int*   src = (const int*)d_in[0];
    const int*   dst = (const int*)d_in[1];
    const float* emb = (const float*)d_in[2];
    const float* W1  = (const float*)d_in[3];
    const float* b1  = (const float*)d_in[4];
    const float* W2  = (const float*)d_in[5];
    const float* b2  = (const float*)d_in[6];
    float* out = (float*)d_out;

    const int n_edges = in_sizes[0];
    const int n_nodes = in_sizes[2] / IN_FEATS;

    const size_t need = (size_t)2 * n_nodes * HIDDEN * sizeof(float);
    const int nb_edges = (n_edges + 255) / 256;

    if (ws_size >= need) {
        float* Ps = (float*)d_ws;
        float* Pd = Ps + (size_t)n_nodes * HIDDEN;
        const int nb_nodes = (n_nodes + 255) / 256;
        precompute_ps_pd<<<nb_nodes, 256, 0, stream>>>(emb, W1, Ps, Pd, n_nodes);
        edge_classify<<<nb_edges, 256, 0, stream>>>(src, dst, Ps, Pd, b1, W2, b2, out, n_edges);
    } else {
        edge_direct<<<nb_edges, 256, 0, stream>>>(src, dst, emb, W1, b1, W2, b2, out, n_edges);
    }
}